// Round 3
// baseline (226.809 us; speedup 1.0000x reference)
//
#include <hip/hip_runtime.h>

// GlobalShift2dV2Portion: x (16, 512, 64, 64) f32.
// ch < 256  : identity copy.
// ch >= 256 : 64x64 image = 4x4 grid of 16x16 pixel blocks; output block
//             t_out=(h/16)*4+(w/16) reads input block t_in=(s+t_out)%16,
//             s=(ch-256)/16.
//
// One workgroup per channel image. Image = 64 rows x 16 float4 = 1024 float4
// = 16 KiB (NOT 4096 float4 — round-2 crash was this unit bug).
// Global read fully contiguous -> LDS, barrier, LDS gather (64B-granular)
// -> fully contiguous global store. Every HBM line is read exactly once by
// exactly one block => no cross-XCD duplicate fetches, streaming both sides.

__global__ __launch_bounds__(256) void GlobalShift2dV2Portion_kernel(
    const float4* __restrict__ in, float4* __restrict__ out) {
    __shared__ float4 lds[1024];              // 16 KiB: one channel image

    int bc = blockIdx.x;                      // b*512 + ch, < 8192
    int ch = bc & 511;
    const float4* src = in  + ((size_t)bc << 10);
    float4*       dst = out + ((size_t)bc << 10);
    int t = threadIdx.x;

    if (ch < 256) {
        // identity half: straight streaming copy, 4 float4 per thread
        #pragma unroll
        for (int k = 0; k < 4; ++k) {
            int o = t + (k << 8);
            dst[o] = src[o];
        }
    } else {
        #pragma unroll
        for (int k = 0; k < 4; ++k) {
            int o = t + (k << 8);
            lds[o] = src[o];
        }
        __syncthreads();
        int s = (ch - 256) >> 4;              // rotation amount, [0,16)
        #pragma unroll
        for (int k = 0; k < 4; ++k) {
            int o  = t + (k << 8);            // output float4 index in image
            int w4 = o & 15;                  // w/4
            int h  = o >> 4;                  // 0..63
            int t_in  = (s + ((h >> 4) << 2) + (w4 >> 2)) & 15;
            int h_in  = ((t_in >> 2) << 4) | (h & 15);
            int w4_in = ((t_in & 3) << 2) | (w4 & 3);
            dst[o] = lds[(h_in << 4) | w4_in];
        }
    }
}

extern "C" void kernel_launch(void* const* d_in, const int* in_sizes, int n_in,
                              void* d_out, int out_size, void* d_ws, size_t ws_size,
                              hipStream_t stream) {
    const float4* in = (const float4*)d_in[0];
    float4* out = (float4*)d_out;
    int blocks = in_sizes[0] / (64 * 64);     // one block per (b, ch) image = 8192
    GlobalShift2dV2Portion_kernel<<<blocks, 256, 0, stream>>>(in, out);
}